// Round 1
// 876.079 us; speedup vs baseline: 1.0723x; 1.0723x over previous
//
#include <hip/hip_runtime.h>
#include <math.h>

#define NROWS 8192
#define DD 128
#define EPSV 1.1920929e-07f
#define ROWS 16   // rows per block in the QKV kernel

typedef float v4f __attribute__((ext_vector_type(4)));

__device__ __forceinline__ float sigmoidf_(float a) { return 1.0f / (1.0f + expf(-a)); }

// ---------------------------------------------------------------------------
// Kernel A: RMSNorm + QKV projection + forget gate for ROWS rows per block.
// w_qkv is read ONCE per 16 rows (vs once per row before): 1.6 GB -> 98 MB L2.
// Results staged into the first 385 floats of each row's out_mem slab
// (q[0:128] | k[128:256] | v[256:384] | f[384]) — kernel B reads them before
// overwriting, block-locally, so no workspace is needed.
// ---------------------------------------------------------------------------
__global__ void __launch_bounds__(128)
qkvf_kernel(const float* __restrict__ x,
            const float* __restrict__ gamma,
            const float* __restrict__ w_qkv,
            const float* __restrict__ w_forget,
            float* __restrict__ out_mem) {
    const int t = threadIdx.x;
    const int rb = blockIdx.x * ROWS;

    __shared__ __align__(16) float s_xn[ROWS][DD];
    __shared__ float s_f[ROWS];

    // ---- Phase 1: RMSNorm + forget-dot. 8 threads per row, 16 floats each.
    {
        const int r = t >> 3;       // row 0..15
        const int l = t & 7;        // lane-in-row 0..7
        const float4* xr = (const float4*)(x + (size_t)(rb + r) * DD);
        float4 xa[4];
        #pragma unroll
        for (int j = 0; j < 4; ++j) xa[j] = xr[l * 4 + j];
        float ss = 0.0f;
        #pragma unroll
        for (int j = 0; j < 4; ++j)
            ss += xa[j].x * xa[j].x + xa[j].y * xa[j].y +
                  xa[j].z * xa[j].z + xa[j].w * xa[j].w;
        #pragma unroll
        for (int off = 1; off < 8; off <<= 1) ss += __shfl_xor(ss, off, 64);
        const float rinv = rsqrtf(ss * (1.0f / DD) + EPSV);

        float fp = 0.0f;
        #pragma unroll
        for (int j = 0; j < 4; ++j) {
            const float4 g  = ((const float4*)gamma)[l * 4 + j];
            const float4 wf = ((const float4*)w_forget)[l * 4 + j];
            float4 xn;
            xn.x = xa[j].x * rinv * g.x;
            xn.y = xa[j].y * rinv * g.y;
            xn.z = xa[j].z * rinv * g.z;
            xn.w = xa[j].w * rinv * g.w;
            fp += xn.x * wf.x + xn.y * wf.y + xn.z * wf.z + xn.w * wf.w;
            ((float4*)s_xn[r])[l * 4 + j] = xn;
        }
        #pragma unroll
        for (int off = 1; off < 8; off <<= 1) fp += __shfl_xor(fp, off, 64);
        if (l == 0) s_f[r] = sigmoidf_(fp);
    }
    __syncthreads();

    // ---- Phase 2: thread t owns cols t (q), 128+t (k), 256+t (v).
    // All three dots share the same broadcast s_xn reads (conflict-free).
    float accq[ROWS], acck[ROWS], accv[ROWS];
    #pragma unroll
    for (int r = 0; r < ROWS; ++r) { accq[r] = 0.f; acck[r] = 0.f; accv[r] = 0.f; }
    const float4* wq = (const float4*)(w_qkv + (size_t)t * DD);
    const float4* wk = (const float4*)(w_qkv + (size_t)(t + DD) * DD);
    const float4* wv = (const float4*)(w_qkv + (size_t)(t + 2 * DD) * DD);
    #pragma unroll 2
    for (int i = 0; i < DD / 4; ++i) {
        const float4 a = wq[i];
        const float4 b = wk[i];
        const float4 c = wv[i];
        #pragma unroll
        for (int r = 0; r < ROWS; ++r) {
            const float4 xx = ((const float4*)s_xn[r])[i];   // broadcast read
            accq[r] = fmaf(a.x, xx.x, accq[r]);
            accq[r] = fmaf(a.y, xx.y, accq[r]);
            accq[r] = fmaf(a.z, xx.z, accq[r]);
            accq[r] = fmaf(a.w, xx.w, accq[r]);
            acck[r] = fmaf(b.x, xx.x, acck[r]);
            acck[r] = fmaf(b.y, xx.y, acck[r]);
            acck[r] = fmaf(b.z, xx.z, acck[r]);
            acck[r] = fmaf(b.w, xx.w, acck[r]);
            accv[r] = fmaf(c.x, xx.x, accv[r]);
            accv[r] = fmaf(c.y, xx.y, accv[r]);
            accv[r] = fmaf(c.z, xx.z, accv[r]);
            accv[r] = fmaf(c.w, xx.w, accv[r]);
        }
    }
    #pragma unroll
    for (int r = 0; r < ROWS; ++r) {
        float* st = out_mem + (size_t)(rb + r) * (DD * DD);
        st[t]          = accq[r] * sigmoidf_(accq[r]);   // silu(q)
        st[DD + t]     = acck[r] * sigmoidf_(acck[r]);   // silu(k)
        st[2 * DD + t] = accv[r];                        // v (no activation)
    }
    if (t < ROWS) out_mem[(size_t)(rb + t) * (DD * DD) + 3 * DD] = s_f[t];
}

// ---------------------------------------------------------------------------
// Kernel B: pure-bandwidth memory lerp + retrieval. ~1.5 KB staged front,
// then streams 128 KB per block. Nontemporal hints keep the 1 GB stream
// from thrashing L2.
// ---------------------------------------------------------------------------
__global__ void __launch_bounds__(256)
stream_kernel(const float* __restrict__ past_mem,
              float* __restrict__ out_retr,
              float* __restrict__ out_mem) {
    const int n = blockIdx.x;
    const int t = threadIdx.x;

    __shared__ __align__(16) float s_q[DD];
    __shared__ __align__(16) float s_k[DD];
    __shared__ __align__(16) float s_v[DD];
    __shared__ float s_fv;
    __shared__ float4 s_red[256];

    const size_t base = (size_t)n * (DD * DD);
    const float* stage = out_mem + base;

    if (t < 96) {
        const float4 val = ((const float4*)stage)[t];
        if (t < 32)      ((float4*)s_q)[t]      = val;
        else if (t < 64) ((float4*)s_k)[t - 32] = val;
        else             ((float4*)s_v)[t - 64] = val;
    }
    if (t == 96) s_fv = stage[3 * DD];
    __syncthreads();   // staged loads complete (vmcnt drained) before we overwrite

    const float f = s_fv;
    const int qc = t & 31;    // float4-column (e = 4*qc..)
    const int dg = t >> 5;    // d-group
    const float4 v4 = ((const float4*)s_v)[qc];
    float4 acc = make_float4(0.0f, 0.0f, 0.0f, 0.0f);
    const v4f* past4 = (const v4f*)(past_mem + base);
    v4f* mem4 = (v4f*)(out_mem + base);

    #pragma unroll 8
    for (int d = dg; d < DD; d += 8) {
        const float kd = s_k[d];   // broadcast, conflict-free
        const float qd = s_q[d];
        const v4f p = __builtin_nontemporal_load(past4 + d * 32 + qc);
        v4f m;
        // mem = past + f*(k*v - past)   (matches jnp lerp order)
        m.x = fmaf(f, fmaf(kd, v4.x, -p.x), p.x);
        m.y = fmaf(f, fmaf(kd, v4.y, -p.y), p.y);
        m.z = fmaf(f, fmaf(kd, v4.z, -p.z), p.z);
        m.w = fmaf(f, fmaf(kd, v4.w, -p.w), p.w);
        __builtin_nontemporal_store(m, mem4 + d * 32 + qc);
        acc.x = fmaf(qd, m.x, acc.x);
        acc.y = fmaf(qd, m.y, acc.y);
        acc.z = fmaf(qd, m.z, acc.z);
        acc.w = fmaf(qd, m.w, acc.w);
    }

    s_red[t] = acc;   // t == dg*32 + qc
    __syncthreads();
    if (t < 32) {
        float4 tot = s_red[t];
        #pragma unroll
        for (int g = 1; g < 8; ++g) {
            float4 r = s_red[g * 32 + t];
            tot.x += r.x; tot.y += r.y; tot.z += r.z; tot.w += r.w;
        }
        ((float4*)(out_retr + (size_t)n * DD))[t] = tot;
    }
}

extern "C" void kernel_launch(void* const* d_in, const int* in_sizes, int n_in,
                              void* d_out, int out_size, void* d_ws, size_t ws_size,
                              hipStream_t stream) {
    (void)in_sizes; (void)n_in; (void)out_size; (void)d_ws; (void)ws_size;
    const float* x        = (const float*)d_in[0];
    const float* past_mem = (const float*)d_in[1];
    const float* gamma    = (const float*)d_in[2];
    const float* w_qkv    = (const float*)d_in[3];
    const float* w_forget = (const float*)d_in[4];
    float* out_retr = (float*)d_out;                         // [N, D]   first output
    float* out_mem  = (float*)d_out + (size_t)NROWS * DD;    // [N, D, D] second output

    qkvf_kernel<<<dim3(NROWS / ROWS), dim3(128), 0, stream>>>(
        x, gamma, w_qkv, w_forget, out_mem);
    stream_kernel<<<dim3(NROWS), dim3(256), 0, stream>>>(
        past_mem, out_retr, out_mem);
}